// Round 15
// baseline (524.128 us; speedup 1.0000x reference)
//
#include <hip/hip_runtime.h>
#include <hip/hip_bf16.h>

#define NB 32    // batch
#define CC 64    // channels
#define VV 500   // nodes
#define LL 64    // time length
#define EE 10    // embedding dim
#define CO 64    // out channels
#define DIL 2    // dilation / shift step
#define VP 512   // padded V for MFMA (k and m padded)
#define SL (VV * LL)   // 32000 flattened (v,l)

typedef unsigned short u16;
typedef unsigned int   u32;
typedef __attribute__((ext_vector_type(8))) short bf16x8;
typedef __attribute__((ext_vector_type(4))) float f32x4;

__device__ __forceinline__ float bf2f(u16 u) {
    union { u32 i; float f; } c; c.i = ((u32)u) << 16; return c.f;
}
__device__ __forceinline__ u16 f2bf(float f) {
    union { float f; u32 i; } c; c.f = f;
    u32 x = c.i;
    u32 r = (x + 0x7fffu + ((x >> 16) & 1u)) >> 16; // RNE
    return (u16)r;
}

// ---------------------------------------------------------------------------
// K0: embedding affine update + mlp_w -> bf16 conversion
// ---------------------------------------------------------------------------
__global__ void emb_kernel(const float* __restrict__ nv1, const float* __restrict__ nv2,
                           const float* __restrict__ et_w, const float* __restrict__ et_b,
                           const float* __restrict__ mlp_w,
                           float* __restrict__ nv1t, float* __restrict__ nv2t,
                           u16* __restrict__ wb) {
    int idx = blockIdx.x * blockDim.x + threadIdx.x;
    if (idx < VV * EE) {
        int v = idx / EE, e = idx - v * EE;
        float s = et_b[e];
        #pragma unroll
        for (int f = 0; f < EE; f++) s += nv1[v * EE + f] * et_w[f * EE + e];
        nv1t[idx] = s;
    } else if (idx < 2 * VV * EE) {
        int k = idx - VV * EE;
        int e = k / VV, v = k - e * VV;
        float s = et_b[e];
        #pragma unroll
        for (int f = 0; f < EE; f++) s += nv2[f * VV + v] * et_w[f * EE + e];
        nv2t[k] = s;
    } else if (idx < 2 * VV * EE + CO * 3 * CC) {
        int k = idx - 2 * VV * EE;
        wb[k] = f2bf(mlp_w[k]);
    }
}

// ---------------------------------------------------------------------------
// K1: both adjacencies in ONE launch (blocks 0..511 -> A0, 512..1023 -> A1).
// ---------------------------------------------------------------------------
__global__ __launch_bounds__(64) void adj2_kernel(const float* __restrict__ nv1,
                                                  const float* __restrict__ nv2,
                                                  const float* __restrict__ nv1t,
                                                  const float* __restrict__ nv2t,
                                                  u16* __restrict__ Atb0,
                                                  u16* __restrict__ Atb1) {
    const int which = blockIdx.x >> 9;          // 0 or 1
    const int v = blockIdx.x & (VP - 1);        // 0..511
    const float* p1 = which ? nv1t : nv1;
    const float* p2 = which ? nv2t : nv2;
    u16* Atb = which ? Atb1 : Atb0;
    const int lane = threadIdx.x;
    if (v >= VV) {
        #pragma unroll
        for (int j = 0; j < 8; j++) Atb[(size_t)(lane + 64 * j) * VP + v] = 0;
        return;
    }
    float e1[EE];
    #pragma unroll
    for (int e = 0; e < EE; e++) e1[e] = p1[v * EE + e];

    float r[8];
    float m = -1e30f;
    #pragma unroll
    for (int j = 0; j < 8; j++) {
        int w = lane + 64 * j;
        if (w < VV) {
            float s = 0.f;
            #pragma unroll
            for (int e = 0; e < EE; e++) s += e1[e] * p2[e * VV + w];
            r[j] = fmaxf(s, 0.f);
            m = fmaxf(m, r[j]);
        } else {
            r[j] = -1e30f;
        }
    }
    #pragma unroll
    for (int off = 32; off > 0; off >>= 1) m = fmaxf(m, __shfl_xor(m, off));

    float p[8];
    float sum = 0.f;
    #pragma unroll
    for (int j = 0; j < 8; j++) {
        int w = lane + 64 * j;
        if (w < VV) { p[j] = expf(r[j] - m); sum += p[j]; }
    }
    #pragma unroll
    for (int off = 32; off > 0; off >>= 1) sum += __shfl_xor(sum, off);
    float inv = 1.f / sum;
    #pragma unroll
    for (int j = 0; j < 8; j++) {
        int w = lane + 64 * j;
        Atb[(size_t)w * VP + v] = (w < VV) ? f2bf(p[j] * inv) : (u16)0;
    }
}

// ---------------------------------------------------------------------------
// K2: FUSED hops, TIME-SHIFTED dual-plane, single shared acc (64 AGPR).
// Schedule (per block, planes P0,P1; Xt[2] = 128 KB; A-frags from L2):
//   stage X0 -> barrier A
//   hop0(P0) 16 steps INTERLEAVED with X1 staging (T14 load-early/write-late)
//   barrier B -> {store x1_0 (async) + rewrite Xt0<-shift(acc)}  [Xt0 unread here]
//   hop0(P1) -> barrier C -> {store x1_1 + rewrite Xt1}          [Xt1 unread here]
//   hop1(P0) -> barrier D -> store x2_0
//   hop1(P1) -> store x2_1
// Stores fire-and-forget before K-loops; staging hides under MFMA.
// acc=64 AGPR + ~100 arch VGPR -> big compiler lookahead slack (cap 256).
// ---------------------------------------------------------------------------
__global__ __launch_bounds__(512, 2) void hops_fused(const float* __restrict__ x,
                                                     const u16* __restrict__ Atb0,
                                                     const u16* __restrict__ Atb1,
                                                     u16* __restrict__ x1g,
                                                     u16* __restrict__ x2g) {
    __shared__ u16 Xt[2][LL * VP];        // 2 x 64 KB
    const int bid = blockIdx.x;
    const int tid = threadIdx.x;
    const int lane = tid & 63;
    const int wv = tid >> 6;
    const int wr = wv * 64;
    const size_t base0 = (size_t)(2 * bid) * (VV * LL);
    const size_t base1 = base0 + (VV * LL);

    const int lquad = lane & 15;
    const int vsub = lane >> 4;
    const int l0 = 4 * lquad;
    const int r15 = lane & 15;
    const int kg = lane >> 4;

    int lrow[4], lswz[4];
    #pragma unroll
    for (int ct = 0; ct < 4; ct++) {
        const int l = ct * 16 + r15;
        lrow[ct] = l * (VP * 2);
        lswz[ct] = (l & 7) << 4;
    }
    const u16* arow0[4];
    const u16* arow1[4];
    #pragma unroll
    for (int rt = 0; rt < 4; rt++) {
        const size_t ro = (size_t)(wr + rt * 16 + r15) * VP + kg * 8;
        arow0[rt] = Atb0 + ro;
        arow1[rt] = Atb1 + ro;
    }

    f32x4 acc[4][4];

    // ---------- helpers ----------
    auto zacc = [&]() {
        #pragma unroll
        for (int rt = 0; rt < 4; rt++)
            #pragma unroll
            for (int ct = 0; ct < 4; ct++)
                acc[rt][ct] = (f32x4){0.f, 0.f, 0.f, 0.f};
    };
    auto kstep = [&](const u16* const arow[4], const char* ldsX, int s) {
        bf16x8 a[4], b[4];
        #pragma unroll
        for (int rt = 0; rt < 4; rt++)
            a[rt] = *(const bf16x8*)(arow[rt] + s * 32);
        #pragma unroll
        for (int ct = 0; ct < 4; ct++)
            b[ct] = *(const bf16x8*)(ldsX + lrow[ct] + ((s * 64 + kg * 16) ^ lswz[ct]));
        __builtin_amdgcn_s_setprio(1);
        #pragma unroll
        for (int rt = 0; rt < 4; rt++)
            #pragma unroll
            for (int ct = 0; ct < 4; ct++)
                acc[rt][ct] = __builtin_amdgcn_mfma_f32_16x16x32_bf16(a[rt], b[ct], acc[rt][ct], 0, 0, 0);
        __builtin_amdgcn_s_setprio(0);
    };
    auto store_plane = [&](u16* xo) {
        #pragma unroll
        for (int rt = 0; rt < 4; rt++) {
            #pragma unroll
            for (int ct = 0; ct < 4; ct++) {
                const int col = ct * 16 + r15;
                const int wbase = wr + rt * 16 + kg * 4;
                f32x4 c = acc[rt][ct];
                #pragma unroll
                for (int r = 0; r < 4; r++) {
                    int w = wbase + r;
                    if (w < VV) xo[w * LL + col] = f2bf(c[r]);
                }
            }
        }
    };
    auto rewrite = [&](char* ldsw) {   // Xt_p[l][v] = x1_p[v][l-DIL], rows l<DIL = 0
        {
            const int l = tid >> 8;          // 0..1 (DIL==2)
            const int j = tid & 255;
            *(u32*)(ldsw + l * (VP * 2) + 4 * j) = 0;
        }
        #pragma unroll
        for (int rt = 0; rt < 4; rt++) {
            const int wb2 = (wr + rt * 16 + kg * 4) * 2;
            #pragma unroll
            for (int ct = 0; ct < 4; ct++) {
                const int col = ct * 16 + r15;
                const int ln = col + DIL;
                if (ln < LL) {
                    f32x4 c = acc[rt][ct];
                    u32 plo = (u32)f2bf(c[0]) | ((u32)f2bf(c[1]) << 16);
                    u32 phi = (u32)f2bf(c[2]) | ((u32)f2bf(c[3]) << 16);
                    const int swz = (ln & 7) << 4;
                    char* p = ldsw + ln * (VP * 2);
                    *(u32*)(p + (wb2 ^ swz)) = plo;
                    *(u32*)(p + ((wb2 + 4) ^ swz)) = phi;
                }
            }
        }
    };
    // staging helpers for plane 1 (interleaved into hop0(P0))
    auto sload = [&](int i, float4& A, float4& B) {
        const int v0 = 2 * (wv * 32 + i * 4 + vsub);
        if (v0 < VV) {
            const float* xa = x + base1 + v0 * LL + l0;
            A = *(const float4*)xa;
            B = *(const float4*)(xa + LL);
        }
    };
    auto swrite = [&](int i, float4 A, float4 B) {
        const int vp = wv * 32 + i * 4 + vsub;
        const int v0 = 2 * vp;
        u32 pk0, pk1, pk2, pk3;
        if (v0 < VV) {
            pk0 = (u32)f2bf(A.x) | ((u32)f2bf(B.x) << 16);
            pk1 = (u32)f2bf(A.y) | ((u32)f2bf(B.y) << 16);
            pk2 = (u32)f2bf(A.z) | ((u32)f2bf(B.z) << 16);
            pk3 = (u32)f2bf(A.w) | ((u32)f2bf(B.w) << 16);
        } else {
            pk0 = pk1 = pk2 = pk3 = 0;
        }
        char* ldsb = (char*)Xt[1];
        const int vb = 4 * vp;
        int l = l0;
        *(u32*)(ldsb + l * (VP * 2) + (vb ^ ((l & 7) << 4))) = pk0; l++;
        *(u32*)(ldsb + l * (VP * 2) + (vb ^ ((l & 7) << 4))) = pk1; l++;
        *(u32*)(ldsb + l * (VP * 2) + (vb ^ ((l & 7) << 4))) = pk2; l++;
        *(u32*)(ldsb + l * (VP * 2) + (vb ^ ((l & 7) << 4))) = pk3;
    };

    // ---------- stage X0 (full, serial) ----------
    {
        char* ldsb = (char*)Xt[0];
        #pragma unroll
        for (int i = 0; i < 8; ++i) {
            const int vp = wv * 32 + i * 4 + vsub;
            const int v0 = 2 * vp;
            u32 pk0, pk1, pk2, pk3;
            if (v0 < VV) {
                const float* xa = x + base0 + v0 * LL + l0;
                float4 fa = *(const float4*)xa;
                float4 fb = *(const float4*)(xa + LL);
                pk0 = (u32)f2bf(fa.x) | ((u32)f2bf(fb.x) << 16);
                pk1 = (u32)f2bf(fa.y) | ((u32)f2bf(fb.y) << 16);
                pk2 = (u32)f2bf(fa.z) | ((u32)f2bf(fb.z) << 16);
                pk3 = (u32)f2bf(fa.w) | ((u32)f2bf(fb.w) << 16);
            } else {
                pk0 = pk1 = pk2 = pk3 = 0;
            }
            const int vb = 4 * vp;
            int l = l0;
            *(u32*)(ldsb + l * (VP * 2) + (vb ^ ((l & 7) << 4))) = pk0; l++;
            *(u32*)(ldsb + l * (VP * 2) + (vb ^ ((l & 7) << 4))) = pk1; l++;
            *(u32*)(ldsb + l * (VP * 2) + (vb ^ ((l & 7) << 4))) = pk2; l++;
            *(u32*)(ldsb + l * (VP * 2) + (vb ^ ((l & 7) << 4))) = pk3;
        }
    }
    float4 fa, fb, fa2, fb2;
    sload(0, fa, fb);          // issue X1 iter-0 loads before the barrier
    __syncthreads();           // A: Xt0 ready

    const char* lds0 = (const char*)Xt[0];
    const char* lds1 = (const char*)Xt[1];

    // ---------- hop0(P0), interleaved with X1 staging ----------
    zacc();
    #pragma unroll
    for (int i = 0; i < 8; ++i) {
        if (i + 1 < 8) sload(i + 1, fa2, fb2);
        kstep(arow0, lds0, 2 * i);
        swrite(i, fa, fb);
        kstep(arow0, lds0, 2 * i + 1);
        fa = fa2; fb = fb2;
    }
    __syncthreads();           // B: Xt1 ready; all waves done reading Xt0

    // ---------- transition: x1_0 out (async) + Xt0 rewrite ----------
    store_plane(x1g + base0);
    rewrite((char*)Xt[0]);     // Xt0 unread until barrier C

    // ---------- hop0(P1) ----------
    zacc();
    #pragma unroll
    for (int s = 0; s < 16; ++s) kstep(arow0, lds1, s);
    __syncthreads();           // C: Xt0' visible; all waves done reading Xt1

    store_plane(x1g + base1);
    rewrite((char*)Xt[1]);     // Xt1 unread until barrier D

    // ---------- hop1(P0) ----------
    zacc();
    #pragma unroll
    for (int s = 0; s < 16; ++s) kstep(arow1, lds0, s);
    __syncthreads();           // D: Xt1' visible

    store_plane(x2g + base0);

    // ---------- hop1(P1) ----------
    zacc();
    #pragma unroll
    for (int s = 0; s < 16; ++s) kstep(arow1, lds1, s);

    store_plane(x2g + base1);
}

// ---------------------------------------------------------------------------
// K3: MLP via MFMA (unchanged — near HBM floor).
// ---------------------------------------------------------------------------
__global__ __launch_bounds__(256, 3) void mlp_mfma(const float* __restrict__ x,
                                                   const u16* __restrict__ x1,
                                                   const u16* __restrict__ x2,
                                                   const u16* __restrict__ wb,
                                                   const float* __restrict__ b,
                                                   float* __restrict__ out) {
    __shared__ u16 Ht[128 * 192];   // 49152 B
    const int bid = blockIdx.x;
    const int n = bid / (SL / 128);
    const int st = bid - n * (SL / 128);
    const int s0 = st * 128;
    const int tid = threadIdx.x;

    const int lane = tid & 63;
    const int wv = tid >> 6;
    const int obase = (wv & 1) * 32;
    const int sbase = (wv >> 1) * 64;
    const int r15 = lane & 15;
    const int kg = lane >> 4;

    bf16x8 afrag[2][6];
    #pragma unroll
    for (int rt = 0; rt < 2; rt++)
        #pragma unroll
        for (int ks = 0; ks < 6; ks++)
            afrag[rt][ks] = *(const bf16x8*)(wb + (obase + rt * 16 + r15) * (3 * CC) + ks * 32 + kg * 8);

    {
        char* ldsb = (char*)Ht;
        const int squad = tid >> 3;
        const int pgroup = tid & 7;
        const int sq0 = 4 * squad;
        #pragma unroll
        for (int i = 0; i < 12; ++i) {
            const int P = i * 8 + pgroup;
            const int c = 2 * P;
            u32 pk0, pk1, pk2, pk3;
            if (i < 4) {
                const float* fsrc = x + ((size_t)n * CC + c) * SL + s0 + sq0;
                float4 va = *(const float4*)fsrc;
                float4 vb = *(const float4*)(fsrc + SL);
                pk0 = (u32)f2bf(va.x) | ((u32)f2bf(vb.x) << 16);
                pk1 = (u32)f2bf(va.y) | ((u32)f2bf(vb.y) << 16);
                pk2 = (u32)f2bf(va.z) | ((u32)f2bf(vb.z) << 16);
                pk3 = (u32)f2bf(va.w) | ((u32)f2bf(vb.w) << 16);
            } else {
                const u16* bsrc = (i < 8)
                    ? x1 + ((size_t)n * CC + (c - CC)) * SL + s0 + sq0
                    : x2 + ((size_t)n * CC + (c - 2 * CC)) * SL + s0 + sq0;
                uint2 va = *(const uint2*)bsrc;
                uint2 vb = *(const uint2*)(bsrc + SL);
                pk0 = (va.x & 0xffffu) | (vb.x << 16);
                pk1 = (va.x >> 16) | (vb.x & 0xffff0000u);
                pk2 = (va.y & 0xffffu) | (vb.y << 16);
                pk3 = (va.y >> 16) | (vb.y & 0xffff0000u);
            }
            int s = sq0;
            *(u32*)(ldsb + s * 384 + ((4 * P) ^ ((s & 7) << 4))) = pk0; s++;
            *(u32*)(ldsb + s * 384 + ((4 * P) ^ ((s & 7) << 4))) = pk1; s++;
            *(u32*)(ldsb + s * 384 + ((4 * P) ^ ((s & 7) << 4))) = pk2; s++;
            *(u32*)(ldsb + s * 384 + ((4 * P) ^ ((s & 7) << 4))) = pk3;
        }
    }
    __syncthreads();

    f32x4 acc[2][4];
    #pragma unroll
    for (int rt = 0; rt < 2; rt++)
        #pragma unroll
        for (int ct = 0; ct < 4; ct++)
            acc[rt][ct] = (f32x4){0.f, 0.f, 0.f, 0.f};

    const char* ldsb = (const char*)Ht;
    #pragma unroll
    for (int ks = 0; ks < 6; ks++) {
        bf16x8 bfr[4];
        #pragma unroll
        for (int ct = 0; ct < 4; ct++) {
            const int s = sbase + ct * 16 + r15;
            bfr[ct] = *(const bf16x8*)(ldsb + s * 384 + ((ks * 64 + kg * 16) ^ ((s & 7) << 4)));
        }
        #pragma unroll
        for (int rt = 0; rt < 2; rt++)
            #pragma unroll
            for (int ct = 0; ct < 4; ct++)
                acc[rt][ct] = __builtin_amdgcn_mfma_f32_16x16x32_bf16(afrag[rt][ks], bfr[ct], acc[rt][ct], 0, 0, 0);
    }

    #pragma unroll
    for (int rt = 0; rt < 2; rt++) {
        #pragma unroll
        for (int r = 0; r < 4; r++) {
            const int o = obase + rt * 16 + kg * 4 + r;
            const float bias = b[o];
            float* orow = out + ((size_t)n * CO + o) * SL + s0 + sbase;
            #pragma unroll
            for (int ct = 0; ct < 4; ct++)
                orow[ct * 16 + r15] = acc[rt][ct][r] + bias;
        }
    }
}

// ---------------------------------------------------------------------------
extern "C" void kernel_launch(void* const* d_in, const int* in_sizes, int n_in,
                              void* d_out, int out_size, void* d_ws, size_t ws_size,
                              hipStream_t stream) {
    const float* x     = (const float*)d_in[0];
    const float* nv1   = (const float*)d_in[1];
    const float* nv2   = (const float*)d_in[2];
    const float* et_w  = (const float*)d_in[3];
    const float* et_b  = (const float*)d_in[4];
    const float* mlp_w = (const float*)d_in[5];
    const float* mlp_b = (const float*)d_in[6];
    float* out = (float*)d_out;

    char* wsb = (char*)d_ws;
    size_t off = 0;
    auto alloc = [&](size_t bytes) {
        size_t o = off;
        off += (bytes + 255) & ~(size_t)255;
        return o;
    };
    u16*   Atb0 = (u16*)(wsb + alloc((size_t)VP * VP * 2));
    u16*   Atb1 = (u16*)(wsb + alloc((size_t)VP * VP * 2));
    float* nv1t = (float*)(wsb + alloc((size_t)VV * EE * 4));
    float* nv2t = (float*)(wsb + alloc((size_t)EE * VV * 4));
    u16*   wb   = (u16*)(wsb + alloc((size_t)CO * 3 * CC * 2));
    u16*   x1   = (u16*)(wsb + alloc((size_t)NB * CC * VV * LL * 2));
    u16*   x2   = (u16*)(wsb + alloc((size_t)NB * CC * VV * LL * 2));
    (void)in_sizes; (void)n_in; (void)out_size; (void)ws_size;

    const int embN = 2 * VV * EE + CO * 3 * CC;
    emb_kernel<<<(embN + 255) / 256, 256, 0, stream>>>(nv1, nv2, et_w, et_b, mlp_w, nv1t, nv2t, wb);
    adj2_kernel<<<2 * VP, 64, 0, stream>>>(nv1, nv2, nv1t, nv2t, Atb0, Atb1);
    hops_fused<<<NB * CC / 2, 512, 0, stream>>>(x, Atb0, Atb1, x1, x2);
    mlp_mfma<<<NB * (SL / 128), 256, 0, stream>>>(x, x1, x2, wb, mlp_b, out);
}

// Round 16
// 427.516 us; speedup vs baseline: 1.2260x; 1.2260x over previous
//
#include <hip/hip_runtime.h>
#include <hip/hip_bf16.h>

#define NB 32    // batch
#define CC 64    // channels
#define VV 500   // nodes
#define LL 64    // time length
#define EE 10    // embedding dim
#define CO 64    // out channels
#define DIL 2    // dilation / shift step
#define VP 512   // padded V for MFMA (k and m padded)
#define SL (VV * LL)   // 32000 flattened (v,l)

typedef unsigned short u16;
typedef unsigned int   u32;
typedef __attribute__((ext_vector_type(8))) short bf16x8;
typedef __attribute__((ext_vector_type(4))) float f32x4;

typedef const __attribute__((address_space(1))) void g_void;
typedef __attribute__((address_space(3))) void l_void;

__device__ __forceinline__ float bf2f(u16 u) {
    union { u32 i; float f; } c; c.i = ((u32)u) << 16; return c.f;
}
__device__ __forceinline__ u16 f2bf(float f) {
    union { float f; u32 i; } c; c.f = f;
    u32 x = c.i;
    u32 r = (x + 0x7fffu + ((x >> 16) & 1u)) >> 16; // RNE
    return (u16)r;
}

// ---------------------------------------------------------------------------
// K0: embedding affine update + mlp_w -> bf16 conversion
// ---------------------------------------------------------------------------
__global__ void emb_kernel(const float* __restrict__ nv1, const float* __restrict__ nv2,
                           const float* __restrict__ et_w, const float* __restrict__ et_b,
                           const float* __restrict__ mlp_w,
                           float* __restrict__ nv1t, float* __restrict__ nv2t,
                           u16* __restrict__ wb) {
    int idx = blockIdx.x * blockDim.x + threadIdx.x;
    if (idx < VV * EE) {
        int v = idx / EE, e = idx - v * EE;
        float s = et_b[e];
        #pragma unroll
        for (int f = 0; f < EE; f++) s += nv1[v * EE + f] * et_w[f * EE + e];
        nv1t[idx] = s;
    } else if (idx < 2 * VV * EE) {
        int k = idx - VV * EE;
        int e = k / VV, v = k - e * VV;
        float s = et_b[e];
        #pragma unroll
        for (int f = 0; f < EE; f++) s += nv2[f * VV + v] * et_w[f * EE + e];
        nv2t[k] = s;
    } else if (idx < 2 * VV * EE + CO * 3 * CC) {
        int k = idx - 2 * VV * EE;
        wb[k] = f2bf(mlp_w[k]);
    }
}

// ---------------------------------------------------------------------------
// K1: both adjacencies in ONE launch (blocks 0..511 -> A0, 512..1023 -> A1).
// ---------------------------------------------------------------------------
__global__ __launch_bounds__(64) void adj2_kernel(const float* __restrict__ nv1,
                                                  const float* __restrict__ nv2,
                                                  const float* __restrict__ nv1t,
                                                  const float* __restrict__ nv2t,
                                                  u16* __restrict__ Atb0,
                                                  u16* __restrict__ Atb1) {
    const int which = blockIdx.x >> 9;          // 0 or 1
    const int v = blockIdx.x & (VP - 1);        // 0..511
    const float* p1 = which ? nv1t : nv1;
    const float* p2 = which ? nv2t : nv2;
    u16* Atb = which ? Atb1 : Atb0;
    const int lane = threadIdx.x;
    if (v >= VV) {
        #pragma unroll
        for (int j = 0; j < 8; j++) Atb[(size_t)(lane + 64 * j) * VP + v] = 0;
        return;
    }
    float e1[EE];
    #pragma unroll
    for (int e = 0; e < EE; e++) e1[e] = p1[v * EE + e];

    float r[8];
    float m = -1e30f;
    #pragma unroll
    for (int j = 0; j < 8; j++) {
        int w = lane + 64 * j;
        if (w < VV) {
            float s = 0.f;
            #pragma unroll
            for (int e = 0; e < EE; e++) s += e1[e] * p2[e * VV + w];
            r[j] = fmaxf(s, 0.f);
            m = fmaxf(m, r[j]);
        } else {
            r[j] = -1e30f;
        }
    }
    #pragma unroll
    for (int off = 32; off > 0; off >>= 1) m = fmaxf(m, __shfl_xor(m, off));

    float p[8];
    float sum = 0.f;
    #pragma unroll
    for (int j = 0; j < 8; j++) {
        int w = lane + 64 * j;
        if (w < VV) { p[j] = expf(r[j] - m); sum += p[j]; }
    }
    #pragma unroll
    for (int off = 32; off > 0; off >>= 1) sum += __shfl_xor(sum, off);
    float inv = 1.f / sum;
    #pragma unroll
    for (int j = 0; j < 8; j++) {
        int w = lane + 64 * j;
        Atb[(size_t)w * VP + v] = (w < VV) ? f2bf(p[j] * inv) : (u16)0;
    }
}

// ---------------------------------------------------------------------------
// K2: FUSED hops — 16 WAVES (1024 thr), wave-private A DMA 3-buf pipeline.
// Wave wv owns 32 output rows; per-wave chunk [32 rows][32 k] = 2 KB (2 DMA
// calls of 1 KB). LDS: Xt 64 KB + 16x3x2 KB = 160 KB -> 1 block/CU but
// 4 waves/SIMD (launch_bounds(1024,4), acc only 32 AGPR). Per-step sync:
// s_waitcnt vmcnt(2) lgkmcnt(0) (own chunk landed, next's 2 calls in
// flight). No block barriers in K-loops; 2 barriers at hop transition.
// ---------------------------------------------------------------------------
__global__ __launch_bounds__(1024, 4) void hops_fused(const float* __restrict__ x,
                                                      const u16* __restrict__ Atb0,
                                                      const u16* __restrict__ Atb1,
                                                      u16* __restrict__ x1g,
                                                      u16* __restrict__ x2g) {
    __shared__ u16 Xt[LL * VP];            // 64 KB
    __shared__ u16 Ab[16][3][32 * 32];     // 16 waves x 3 bufs x 2 KB = 96 KB
    const int tid = threadIdx.x;
    const int lane = tid & 63;
    const int wv = tid >> 6;               // 0..15
    const int wr = wv * 32;
    const size_t base = (size_t)blockIdx.x * (VV * LL);

    // ---- per-thread constant DMA offsets (wave-private 2 KB chunk) ----
    // chunk layout: [32 rows][4 cells of 16B], cell = kgroup ^ ((row>>1)&3)
    int growoff[2], ldsoff[2];
    #pragma unroll
    for (int j = 0; j < 2; ++j) {
        const int lin = j * 1024 + lane * 16;       // byte offset in 2 KB chunk
        const int wl = lin >> 6;                    // local row 0..31
        const int cell = ((lin >> 4) & 3) ^ ((wl >> 1) & 3);
        ldsoff[j] = lin;
        growoff[j] = (wr + wl) * VP + cell * 8;     // u16 elements
    }
    char* mybuf[3];
    #pragma unroll
    for (int k = 0; k < 3; ++k) mybuf[k] = (char*)&Ab[wv][k][0];

    auto issue_chunk = [&](const u16* Asrc, int kb, char* dst) {
        #pragma unroll
        for (int j = 0; j < 2; ++j)
            __builtin_amdgcn_global_load_lds(
                (g_void*)(Asrc + growoff[j] + kb),
                (l_void*)(dst + ldsoff[j]), 16, 0, 0);
    };

    // ---- prologue: kick chunks 0,1; stage Xt ----
    issue_chunk(Atb0, 0, mybuf[0]);
    issue_chunk(Atb0, 32, mybuf[1]);

    {
        char* ldsb = (char*)Xt;
        const int lquad = lane & 15;
        const int vsub = lane >> 4;     // 0..3
        const int l0 = 4 * lquad;
        #pragma unroll
        for (int i = 0; i < 4; ++i) {
            const int vp = wv * 16 + i * 4 + vsub;  // v-pair 0..255
            const int v0 = 2 * vp;
            u32 pk0, pk1, pk2, pk3;
            if (v0 < VV) {
                const float* xa = x + base + v0 * LL + l0;
                float4 fa = *(const float4*)xa;
                float4 fb = *(const float4*)(xa + LL);
                pk0 = (u32)f2bf(fa.x) | ((u32)f2bf(fb.x) << 16);
                pk1 = (u32)f2bf(fa.y) | ((u32)f2bf(fb.y) << 16);
                pk2 = (u32)f2bf(fa.z) | ((u32)f2bf(fb.z) << 16);
                pk3 = (u32)f2bf(fa.w) | ((u32)f2bf(fb.w) << 16);
            } else {
                pk0 = pk1 = pk2 = pk3 = 0;
            }
            const int vb = 4 * vp;
            int l = l0;
            *(u32*)(ldsb + l * (VP * 2) + (vb ^ ((l & 7) << 4))) = pk0; l++;
            *(u32*)(ldsb + l * (VP * 2) + (vb ^ ((l & 7) << 4))) = pk1; l++;
            *(u32*)(ldsb + l * (VP * 2) + (vb ^ ((l & 7) << 4))) = pk2; l++;
            *(u32*)(ldsb + l * (VP * 2) + (vb ^ ((l & 7) << 4))) = pk3;
        }
    }
    __syncthreads();   // Xt staged; chunks 0,1 landed (full drain)

    // ---- compute geometry (thread-constant) ----
    const int r15 = lane & 15;
    const int kg = lane >> 4;
    const char* ldsb = (const char*)Xt;
    int lrow[4], lswz[4], aoff[2];
    #pragma unroll
    for (int ct = 0; ct < 4; ct++) {
        const int l = ct * 16 + r15;
        lrow[ct] = l * (VP * 2);
        lswz[ct] = (l & 7) << 4;
    }
    #pragma unroll
    for (int rt = 0; rt < 2; rt++) {
        const int wl = rt * 16 + r15;   // local row 0..31
        aoff[rt] = wl * 64 + ((kg ^ ((wl >> 1) & 3)) << 4);   // bytes in chunk
    }

    f32x4 acc[2][4];
    #pragma unroll
    for (int rt = 0; rt < 2; rt++)
        #pragma unroll
        for (int ct = 0; ct < 4; ct++)
            acc[rt][ct] = (f32x4){0.f, 0.f, 0.f, 0.f};

    // ==================== hop 0: steps 0..15 (no barriers) ====================
    #pragma unroll
    for (int s = 0; s < 16; ++s) {
        asm volatile("s_waitcnt vmcnt(2) lgkmcnt(0)" ::: "memory");
        const int g1 = s + 2;   // chunk to issue
        issue_chunk(g1 < 16 ? Atb0 : Atb1, (g1 & 15) * 32, mybuf[g1 % 3]);

        const char* ac = mybuf[s % 3];
        bf16x8 a[2], b[4];
        #pragma unroll
        for (int rt = 0; rt < 2; rt++)
            a[rt] = *(const bf16x8*)(ac + aoff[rt]);
        #pragma unroll
        for (int ct = 0; ct < 4; ct++)
            b[ct] = *(const bf16x8*)(ldsb + lrow[ct] + ((s * 64 + kg * 16) ^ lswz[ct]));
        __builtin_amdgcn_s_setprio(1);
        #pragma unroll
        for (int rt = 0; rt < 2; rt++)
            #pragma unroll
            for (int ct = 0; ct < 4; ct++)
                acc[rt][ct] = __builtin_amdgcn_mfma_f32_16x16x32_bf16(a[rt], b[ct], acc[rt][ct], 0, 0, 0);
        __builtin_amdgcn_s_setprio(0);
    }

    // ---- transition: store x1, rewrite Xt shifted ----
    {
        u16* xo = x1g + base;
        #pragma unroll
        for (int rt = 0; rt < 2; rt++) {
            #pragma unroll
            for (int ct = 0; ct < 4; ct++) {
                const int col = ct * 16 + r15;
                const int wbase = wr + rt * 16 + kg * 4;
                f32x4 c = acc[rt][ct];
                #pragma unroll
                for (int r = 0; r < 4; r++) {
                    int w = wbase + r;
                    if (w < VV) xo[w * LL + col] = f2bf(c[r]);
                }
            }
        }
    }
    __syncthreads();   // all waves done reading Xt (full vm/lgkm drain)
    {
        char* ldsw = (char*)Xt;
        if (tid < 512) {
            const int l = tid >> 8;          // 0..1 (DIL==2)
            const int j = tid & 255;
            *(u32*)(ldsw + l * (VP * 2) + 4 * j) = 0;
        }
        #pragma unroll
        for (int rt = 0; rt < 2; rt++) {
            const int wb2 = (wr + rt * 16 + kg * 4) * 2;   // byte offset of w in row
            #pragma unroll
            for (int ct = 0; ct < 4; ct++) {
                const int col = ct * 16 + r15;
                const int ln = col + DIL;
                if (ln < LL) {
                    f32x4 c = acc[rt][ct];
                    u32 plo = (u32)f2bf(c[0]) | ((u32)f2bf(c[1]) << 16);
                    u32 phi = (u32)f2bf(c[2]) | ((u32)f2bf(c[3]) << 16);
                    const int swz = (ln & 7) << 4;
                    char* p = ldsw + ln * (VP * 2);
                    *(u32*)(p + (wb2 ^ swz)) = plo;
                    *(u32*)(p + ((wb2 + 4) ^ swz)) = phi;
                }
            }
        }
    }
    __syncthreads();

    #pragma unroll
    for (int rt = 0; rt < 2; rt++)
        #pragma unroll
        for (int ct = 0; ct < 4; ct++)
            acc[rt][ct] = (f32x4){0.f, 0.f, 0.f, 0.f};

    // ==================== hop 1: steps 16..31 (no barriers) ====================
    #pragma unroll
    for (int s = 16; s < 32; ++s) {
        if (s == 31) {
            asm volatile("s_waitcnt vmcnt(0) lgkmcnt(0)" ::: "memory");
        } else {
            asm volatile("s_waitcnt vmcnt(2) lgkmcnt(0)" ::: "memory");
        }
        const int g1 = s + 2;
        if (g1 < 32)
            issue_chunk(Atb1, (g1 & 15) * 32, mybuf[g1 % 3]);

        const char* ac = mybuf[s % 3];
        const int kk = s - 16;
        bf16x8 a[2], b[4];
        #pragma unroll
        for (int rt = 0; rt < 2; rt++)
            a[rt] = *(const bf16x8*)(ac + aoff[rt]);
        #pragma unroll
        for (int ct = 0; ct < 4; ct++)
            b[ct] = *(const bf16x8*)(ldsb + lrow[ct] + ((kk * 64 + kg * 16) ^ lswz[ct]));
        __builtin_amdgcn_s_setprio(1);
        #pragma unroll
        for (int rt = 0; rt < 2; rt++)
            #pragma unroll
            for (int ct = 0; ct < 4; ct++)
                acc[rt][ct] = __builtin_amdgcn_mfma_f32_16x16x32_bf16(a[rt], b[ct], acc[rt][ct], 0, 0, 0);
        __builtin_amdgcn_s_setprio(0);
    }

    // ---- store x2 ----
    {
        u16* xo = x2g + base;
        #pragma unroll
        for (int rt = 0; rt < 2; rt++) {
            #pragma unroll
            for (int ct = 0; ct < 4; ct++) {
                const int col = ct * 16 + r15;
                const int wbase = wr + rt * 16 + kg * 4;
                f32x4 c = acc[rt][ct];
                #pragma unroll
                for (int r = 0; r < 4; r++) {
                    int w = wbase + r;
                    if (w < VV) xo[w * LL + col] = f2bf(c[r]);
                }
            }
        }
    }
}

// ---------------------------------------------------------------------------
// K3: MLP via MFMA (unchanged — near HBM floor).
// ---------------------------------------------------------------------------
__global__ __launch_bounds__(256, 3) void mlp_mfma(const float* __restrict__ x,
                                                   const u16* __restrict__ x1,
                                                   const u16* __restrict__ x2,
                                                   const u16* __restrict__ wb,
                                                   const float* __restrict__ b,
                                                   float* __restrict__ out) {
    __shared__ u16 Ht[128 * 192];   // 49152 B
    const int bid = blockIdx.x;
    const int n = bid / (SL / 128);
    const int st = bid - n * (SL / 128);
    const int s0 = st * 128;
    const int tid = threadIdx.x;

    const int lane = tid & 63;
    const int wv = tid >> 6;
    const int obase = (wv & 1) * 32;
    const int sbase = (wv >> 1) * 64;
    const int r15 = lane & 15;
    const int kg = lane >> 4;

    bf16x8 afrag[2][6];
    #pragma unroll
    for (int rt = 0; rt < 2; rt++)
        #pragma unroll
        for (int ks = 0; ks < 6; ks++)
            afrag[rt][ks] = *(const bf16x8*)(wb + (obase + rt * 16 + r15) * (3 * CC) + ks * 32 + kg * 8);

    {
        char* ldsb = (char*)Ht;
        const int squad = tid >> 3;
        const int pgroup = tid & 7;
        const int sq0 = 4 * squad;
        #pragma unroll
        for (int i = 0; i < 12; ++i) {
            const int P = i * 8 + pgroup;
            const int c = 2 * P;
            u32 pk0, pk1, pk2, pk3;
            if (i < 4) {
                const float* fsrc = x + ((size_t)n * CC + c) * SL + s0 + sq0;
                float4 va = *(const float4*)fsrc;
                float4 vb = *(const float4*)(fsrc + SL);
                pk0 = (u32)f2bf(va.x) | ((u32)f2bf(vb.x) << 16);
                pk1 = (u32)f2bf(va.y) | ((u32)f2bf(vb.y) << 16);
                pk2 = (u32)f2bf(va.z) | ((u32)f2bf(vb.z) << 16);
                pk3 = (u32)f2bf(va.w) | ((u32)f2bf(vb.w) << 16);
            } else {
                const u16* bsrc = (i < 8)
                    ? x1 + ((size_t)n * CC + (c - CC)) * SL + s0 + sq0
                    : x2 + ((size_t)n * CC + (c - 2 * CC)) * SL + s0 + sq0;
                uint2 va = *(const uint2*)bsrc;
                uint2 vb = *(const uint2*)(bsrc + SL);
                pk0 = (va.x & 0xffffu) | (vb.x << 16);
                pk1 = (va.x >> 16) | (vb.x & 0xffff0000u);
                pk2 = (va.y & 0xffffu) | (vb.y << 16);
                pk3 = (va.y >> 16) | (vb.y & 0xffff0000u);
            }
            int s = sq0;
            *(u32*)(ldsb + s * 384 + ((4 * P) ^ ((s & 7) << 4))) = pk0; s++;
            *(u32*)(ldsb + s * 384 + ((4 * P) ^ ((s & 7) << 4))) = pk1; s++;
            *(u32*)(ldsb + s * 384 + ((4 * P) ^ ((s & 7) << 4))) = pk2; s++;
            *(u32*)(ldsb + s * 384 + ((4 * P) ^ ((s & 7) << 4))) = pk3;
        }
    }
    __syncthreads();

    f32x4 acc[2][4];
    #pragma unroll
    for (int rt = 0; rt < 2; rt++)
        #pragma unroll
        for (int ct = 0; ct < 4; ct++)
            acc[rt][ct] = (f32x4){0.f, 0.f, 0.f, 0.f};

    const char* ldsb = (const char*)Ht;
    #pragma unroll
    for (int ks = 0; ks < 6; ks++) {
        bf16x8 bfr[4];
        #pragma unroll
        for (int ct = 0; ct < 4; ct++) {
            const int s = sbase + ct * 16 + r15;
            bfr[ct] = *(const bf16x8*)(ldsb + s * 384 + ((ks * 64 + kg * 16) ^ ((s & 7) << 4)));
        }
        #pragma unroll
        for (int rt = 0; rt < 2; rt++)
            #pragma unroll
            for (int ct = 0; ct < 4; ct++)
                acc[rt][ct] = __builtin_amdgcn_mfma_f32_16x16x32_bf16(afrag[rt][ks], bfr[ct], acc[rt][ct], 0, 0, 0);
    }

    #pragma unroll
    for (int rt = 0; rt < 2; rt++) {
        #pragma unroll
        for (int r = 0; r < 4; r++) {
            const int o = obase + rt * 16 + kg * 4 + r;
            const float bias = b[o];
            float* orow = out + ((size_t)n * CO + o) * SL + s0 + sbase;
            #pragma unroll
            for (int ct = 0; ct < 4; ct++)
                orow[ct * 16 + r15] = acc[rt][ct][r] + bias;
        }
    }
}

// ---------------------------------------------------------------------------
extern "C" void kernel_launch(void* const* d_in, const int* in_sizes, int n_in,
                              void* d_out, int out_size, void* d_ws, size_t ws_size,
                              hipStream_t stream) {
    const float* x     = (const float*)d_in[0];
    const float* nv1   = (const float*)d_in[1];
    const float* nv2   = (const float*)d_in[2];
    const float* et_w  = (const float*)d_in[3];
    const float* et_b  = (const float*)d_in[4];
    const float* mlp_w = (const float*)d_in[5];
    const float* mlp_b = (const float*)d_in[6];
    float* out = (float*)d_out;

    char* wsb = (char*)d_ws;
    size_t off = 0;
    auto alloc = [&](size_t bytes) {
        size_t o = off;
        off += (bytes + 255) & ~(size_t)255;
        return o;
    };
    u16*   Atb0 = (u16*)(wsb + alloc((size_t)VP * VP * 2));
    u16*   Atb1 = (u16*)(wsb + alloc((size_t)VP * VP * 2));
    float* nv1t = (float*)(wsb + alloc((size_t)VV * EE * 4));
    float* nv2t = (float*)(wsb + alloc((size_t)EE * VV * 4));
    u16*   wb   = (u16*)(wsb + alloc((size_t)CO * 3 * CC * 2));
    u16*   x1   = (u16*)(wsb + alloc((size_t)NB * CC * VV * LL * 2));
    u16*   x2   = (u16*)(wsb + alloc((size_t)NB * CC * VV * LL * 2));
    (void)in_sizes; (void)n_in; (void)out_size; (void)ws_size;

    const int embN = 2 * VV * EE + CO * 3 * CC;
    emb_kernel<<<(embN + 255) / 256, 256, 0, stream>>>(nv1, nv2, et_w, et_b, mlp_w, nv1t, nv2t, wb);
    adj2_kernel<<<2 * VP, 64, 0, stream>>>(nv1, nv2, nv1t, nv2t, Atb0, Atb1);
    hops_fused<<<NB * CC, 1024, 0, stream>>>(x, Atb0, Atb1, x1, x2);
    mlp_mfma<<<NB * (SL / 128), 256, 0, stream>>>(x, x1, x2, wb, mlp_b, out);
}